// Round 1
// baseline (1562.024 us; speedup 1.0000x reference)
//
#include <hip/hip_runtime.h>
#include <hip/hip_bf16.h>

typedef __bf16 bf16x8 __attribute__((ext_vector_type(8)));
typedef float  f32x4  __attribute__((ext_vector_type(4)));

#define NB 32
#define NS 2048
#define ND 512
#define NH 512
#define NROWS (NB*NS)

// ---------------------------------------------------------------------------
// prep: W[d][h] (f32) -> wT[m][h][d] (bf16), m in {q,k,v}
// ---------------------------------------------------------------------------
__global__ void prep_w(const float* __restrict__ Wq, const float* __restrict__ Wk,
                       const float* __restrict__ Wv, __bf16* __restrict__ wT) {
  int i = blockIdx.x * blockDim.x + threadIdx.x;
  const int total = 3 * ND * NH;
  for (; i < total; i += gridDim.x * blockDim.x) {
    int m = i / (ND * NH);
    int rem = i - m * (ND * NH);
    int h = rem >> 9;
    int d = rem & 511;
    const float* W = (m == 0) ? Wq : ((m == 1) ? Wk : Wv);
    wT[i] = (__bf16)W[(size_t)d * NH + h];
  }
}

// ---------------------------------------------------------------------------
// K1: projection GEMM + row softmax stats.
//  grid (2048, 3): 32 rows/WG, mode = blockIdx.y (0:q->p, 1:k->k,L, 2:v->vT)
//  512 threads = 8 waves: wave w: it = w>>2 (row 16-tile), cs = w&3 (128-col slice)
// LDS: x_lds[32][40]bf16 | w_lds[512][40]bf16 (aliased by ostage[32][520]) | red[2][4][32]f32
// ---------------------------------------------------------------------------
#define K1_XOFF 0
#define K1_WOFF 2560
#define K1_RMAX 43520
#define K1_RSUM 44032
#define K1_LDS  44544

__global__ __launch_bounds__(512, 2)
void proj_kernel(const float* __restrict__ x, const __bf16* __restrict__ wT,
                 __bf16* __restrict__ p_out, __bf16* __restrict__ k_out,
                 float* __restrict__ L_out, __bf16* __restrict__ vT_out)
{
  __shared__ __align__(16) char smem[K1_LDS];
  char* x_lds = smem + K1_XOFF;   // row stride 80 B
  char* w_lds = smem + K1_WOFF;   // row stride 80 B
  float* redmax = (float*)(smem + K1_RMAX);   // [4][32]
  float* redsum = (float*)(smem + K1_RSUM);   // [4][32]
  char* ostage = smem + K1_WOFF;  // [32][520] bf16, row stride 1040 B

  const int tid = threadIdx.x;
  const int w = tid >> 6, lane = tid & 63, l15 = lane & 15, g = lane >> 4;
  const int it = w >> 2, cs = w & 3;
  const int mode = blockIdx.y;
  const int r0 = blockIdx.x * 32;           // global row
  const int b = r0 >> 11, s_in_b = r0 & (NS - 1);
  const __bf16* Wm = wT + (size_t)mode * (ND * NH);

  f32x4 acc[8];
  #pragma unroll
  for (int i = 0; i < 8; ++i) acc[i] = (f32x4){0.f, 0.f, 0.f, 0.f};

  for (int d0 = 0; d0 < ND; d0 += 32) {
    __syncthreads();
    if (tid < 256) {          // x tile [32 rows][32 d] f32 -> bf16
      int row = tid >> 3, seg = tid & 7;
      float4 v = *(const float4*)(x + (size_t)(r0 + row) * ND + d0 + seg * 4);
      union { __bf16 h4[4]; ushort4 u; } cv;
      cv.h4[0] = (__bf16)v.x; cv.h4[1] = (__bf16)v.y;
      cv.h4[2] = (__bf16)v.z; cv.h4[3] = (__bf16)v.w;
      *(ushort4*)(x_lds + row * 80 + seg * 8) = cv.u;
    }
    {                         // w tile [512 h][32 d]
      int rr = tid >> 2, seg = tid & 3;
      #pragma unroll
      for (int p = 0; p < 4; ++p) {
        int h = p * 128 + rr;
        bf16x8 v = *(const bf16x8*)(Wm + (size_t)h * ND + d0 + seg * 8);
        *(bf16x8*)(w_lds + h * 80 + seg * 16) = v;
      }
    }
    __syncthreads();
    bf16x8 a = *(const bf16x8*)(x_lds + (it * 16 + l15) * 80 + g * 16);
    #pragma unroll
    for (int ht = 0; ht < 8; ++ht) {
      bf16x8 bb = *(const bf16x8*)(w_lds + (cs * 128 + ht * 16 + l15) * 80 + g * 16);
      acc[ht] = __builtin_amdgcn_mfma_f32_16x16x32_bf16(a, bb, acc[ht], 0, 0, 0);
    }
  }
  __syncthreads();

  if (mode == 2) {            // v: write transposed vT[b][h][s], packed 4 bf16
    #pragma unroll
    for (int ht = 0; ht < 8; ++ht) {
      int h = cs * 128 + ht * 16 + l15;
      union { __bf16 h4[4]; ushort4 u; } cv;
      #pragma unroll
      for (int r = 0; r < 4; ++r) cv.h4[r] = (__bf16)acc[ht][r];
      size_t addr = ((size_t)(b * NH + h)) * NS + s_in_b + it * 16 + g * 4;
      *(ushort4*)(vT_out + addr) = cv.u;
    }
    return;
  }

  // modes 0/1: row max / sumexp over 512 cols
  float rmax[4], rsum[4], mrow[4], tsum[4];
  #pragma unroll
  for (int r = 0; r < 4; ++r) {
    float v = acc[0][r];
    #pragma unroll
    for (int ht = 1; ht < 8; ++ht) v = fmaxf(v, acc[ht][r]);
    for (int m2 = 1; m2 < 16; m2 <<= 1) v = fmaxf(v, __shfl_xor(v, m2));
    rmax[r] = v;
  }
  if (l15 == 0) {
    #pragma unroll
    for (int r = 0; r < 4; ++r) redmax[cs * 32 + it * 16 + g * 4 + r] = rmax[r];
  }
  __syncthreads();
  #pragma unroll
  for (int r = 0; r < 4; ++r) {
    int row = it * 16 + g * 4 + r;
    mrow[r] = fmaxf(fmaxf(redmax[row], redmax[32 + row]),
                    fmaxf(redmax[64 + row], redmax[96 + row]));
  }
  #pragma unroll
  for (int r = 0; r < 4; ++r) {
    float s = 0.f;
    #pragma unroll
    for (int ht = 0; ht < 8; ++ht) s += __expf(acc[ht][r] - mrow[r]);
    for (int m2 = 1; m2 < 16; m2 <<= 1) s += __shfl_xor(s, m2);
    rsum[r] = s;
  }
  if (l15 == 0) {
    #pragma unroll
    for (int r = 0; r < 4; ++r) redsum[cs * 32 + it * 16 + g * 4 + r] = rsum[r];
  }
  __syncthreads();
  #pragma unroll
  for (int r = 0; r < 4; ++r) {
    int row = it * 16 + g * 4 + r;
    tsum[r] = redsum[row] + redsum[32 + row] + redsum[64 + row] + redsum[96 + row];
  }

  float inv[4];
  #pragma unroll
  for (int r = 0; r < 4; ++r) inv[r] = 1.f / tsum[r];
  #pragma unroll
  for (int ht = 0; ht < 8; ++ht) {
    int col = cs * 128 + ht * 16 + l15;
    #pragma unroll
    for (int r = 0; r < 4; ++r) {
      int row = it * 16 + g * 4 + r;
      float val = (mode == 0) ? __expf(acc[ht][r] - mrow[r]) * inv[r] : acc[ht][r];
      *((__bf16*)(ostage + row * 1040 + col * 2)) = (__bf16)val;
    }
  }
  if (mode == 1 && cs == 0 && l15 == 0) {
    #pragma unroll
    for (int r = 0; r < 4; ++r) {
      int row = it * 16 + g * 4 + r;
      L_out[r0 + row] = mrow[r] + logf(tsum[r]);
    }
  }
  __syncthreads();
  // copy ostage -> global (coalesced)
  {
    __bf16* dst_base = (mode == 0) ? p_out : k_out;
    int trow = tid >> 4, tseg = tid & 15;
    const char* srcp = ostage + trow * 1040 + tseg * 64;
    __bf16* dstp = dst_base + (size_t)(r0 + trow) * NH + tseg * 32;
    #pragma unroll
    for (int u = 0; u < 4; ++u)
      *(bf16x8*)(dstp + u * 8) = *(const bf16x8*)(srcp + u * 16);
  }
}

// ---------------------------------------------------------------------------
// K2: flash attention. scores[i,j] = dot(p_i, k_j) - L[j]; out = softmax_j @ v
//  grid 2048 (XCD-swizzled): block = (batch, 32-row i-tile). 512 thr = 8 waves.
//  wave w: scores tile (it=w>>2, jt=w&3); PV h-slice hs=w*64.
// ---------------------------------------------------------------------------
#define K2_KSTR 1040      // 520 bf16/row
#define K2_VSTR 144       // 72 bf16/row
#define K2_PSTR 144
#define OFF_V 66560
#define OFF_P 140288
#define OFF_L 144896
#define OFF_MP 145152
#define OFF_SP 145664
#define OFF_MR 146176
#define OFF_LR 146304
#define K2_LDS 146432

__global__ __launch_bounds__(512, 2)
void attn_kernel(const __bf16* __restrict__ p_all, const __bf16* __restrict__ k_all,
                 const float* __restrict__ L_all, const __bf16* __restrict__ vT_all,
                 float* __restrict__ out)
{
  __shared__ __align__(16) char smem[K2_LDS];
  char* Kb = smem;
  char* Vb = smem + OFF_V;
  char* Pb = smem + OFF_P;
  float* Lt   = (float*)(smem + OFF_L);
  float* Mp   = (float*)(smem + OFF_MP);
  float* Sp   = (float*)(smem + OFF_SP);
  float* mrun = (float*)(smem + OFF_MR);
  float* lrun = (float*)(smem + OFF_LR);

  int bid = blockIdx.x;
  int lb = (bid & 7) * 256 + (bid >> 3);     // XCD swizzle (2048 = 8*256)
  int b = lb >> 6, ib = lb & 63;
  int i0 = ib * 32;

  const __bf16* Pg = p_all + (size_t)b * NS * NH;
  const __bf16* Kg = k_all + (size_t)b * NS * NH;
  const float*  Lg = L_all + (size_t)b * NS;
  const __bf16* Vg = vT_all + (size_t)b * NH * NS;
  float* Og = out + (size_t)(b * NS + i0) * NH;

  const int tid = threadIdx.x;
  const int w = tid >> 6, lane = tid & 63, l15 = lane & 15, g = lane >> 4;
  const int it = w >> 2, jt = w & 3;
  const int hs = w * 64;
  const int srow = tid >> 3, sseg = tid & 7;

  bf16x8 qf[16];
  {
    const __bf16* qrow = Pg + (size_t)(i0 + it * 16 + l15) * NH + g * 8;
    #pragma unroll
    for (int kk = 0; kk < 16; ++kk) qf[kk] = *(const bf16x8*)(qrow + kk * 32);
  }

  f32x4 o[2][4];
  #pragma unroll
  for (int i2 = 0; i2 < 2; ++i2)
    #pragma unroll
    for (int ht = 0; ht < 4; ++ht) o[i2][ht] = (f32x4){0.f, 0.f, 0.f, 0.f};

  if (tid < 32) { mrun[tid] = -1e30f; lrun[tid] = 0.f; }

  for (int j0 = 0; j0 < NS; j0 += 64) {
    __syncthreads();
    {   // stage K [64 j][512 h]: coalesced 128B rows, conflict-free ds writes
      const __bf16* src = Kg + (size_t)(j0 + srow) * NH + sseg * 8;
      char* dst = Kb + srow * K2_KSTR + sseg * 16;
      #pragma unroll
      for (int u = 0; u < 8; ++u)
        *(bf16x8*)(dst + u * 128) = *(const bf16x8*)(src + u * 64);
    }
    {   // stage V^T [512 h][64 j]
      #pragma unroll
      for (int p = 0; p < 8; ++p) {
        int h = p * 64 + srow;
        *(bf16x8*)(Vb + h * K2_VSTR + sseg * 16) =
            *(const bf16x8*)(Vg + (size_t)h * NS + j0 + sseg * 8);
      }
    }
    if (tid < 64) Lt[tid] = Lg[j0 + tid];
    __syncthreads();

    // ---- scores (16x16 tile per wave) ----
    f32x4 s = (f32x4){0.f, 0.f, 0.f, 0.f};
    #pragma unroll
    for (int kk = 0; kk < 16; ++kk) {
      bf16x8 kf = *(const bf16x8*)(Kb + (jt * 16 + l15) * K2_KSTR + kk * 64 + g * 16);
      s = __builtin_amdgcn_mfma_f32_16x16x32_bf16(qf[kk], kf, s, 0, 0, 0);
    }
    float Lj = Lt[jt * 16 + l15];
    float sv[4];
    #pragma unroll
    for (int r = 0; r < 4; ++r) sv[r] = s[r] - Lj;

    // ---- online softmax bookkeeping ----
    float rm[4];
    #pragma unroll
    for (int r = 0; r < 4; ++r) {
      float v = sv[r];
      for (int m2 = 1; m2 < 16; m2 <<= 1) v = fmaxf(v, __shfl_xor(v, m2));
      rm[r] = v;
    }
    if (l15 == 0) {
      #pragma unroll
      for (int r = 0; r < 4; ++r) Mp[jt * 32 + it * 16 + g * 4 + r] = rm[r];
    }
    __syncthreads();

    float pv[4], al[2][4];
    #pragma unroll
    for (int i2 = 0; i2 < 2; ++i2)
      #pragma unroll
      for (int r = 0; r < 4; ++r) {
        int row = i2 * 16 + g * 4 + r;
        float mo = mrun[row];
        float mn = fmaxf(fmaxf(Mp[row], Mp[32 + row]), fmaxf(Mp[64 + row], Mp[96 + row]));
        mn = fmaxf(mn, mo);
        al[i2][r] = __expf(mo - mn);
        if (i2 == it) pv[r] = __expf(sv[r] - mn);
      }
    #pragma unroll
    for (int r = 0; r < 4; ++r) {
      float v = pv[r];
      for (int m2 = 1; m2 < 16; m2 <<= 1) v += __shfl_xor(v, m2);
      if (l15 == 0) Sp[jt * 32 + it * 16 + g * 4 + r] = v;
    }
    #pragma unroll
    for (int r = 0; r < 4; ++r)
      *((__bf16*)(Pb + (it * 16 + g * 4 + r) * K2_PSTR + (jt * 16 + l15) * 2)) = (__bf16)pv[r];
    __syncthreads();

    if (jt == 0 && l15 == 0) {
      #pragma unroll
      for (int r = 0; r < 4; ++r) {
        int row = it * 16 + g * 4 + r;
        float mo = mrun[row];
        float mn = fmaxf(fmaxf(Mp[row], Mp[32 + row]), fmaxf(Mp[64 + row], Mp[96 + row]));
        mn = fmaxf(mn, mo);
        lrun[row] = lrun[row] * __expf(mo - mn)
                  + (Sp[row] + Sp[32 + row] + Sp[64 + row] + Sp[96 + row]);
        mrun[row] = mn;
      }
    }
    #pragma unroll
    for (int i2 = 0; i2 < 2; ++i2)
      #pragma unroll
      for (int ht = 0; ht < 4; ++ht)
        #pragma unroll
        for (int r = 0; r < 4; ++r) o[i2][ht][r] *= al[i2][r];

    // ---- PV ----
    #pragma unroll
    for (int kk = 0; kk < 2; ++kk) {
      bf16x8 pa0 = *(const bf16x8*)(Pb + l15 * K2_PSTR + kk * 64 + g * 16);
      bf16x8 pa1 = *(const bf16x8*)(Pb + (16 + l15) * K2_PSTR + kk * 64 + g * 16);
      #pragma unroll
      for (int ht = 0; ht < 4; ++ht) {
        bf16x8 vb = *(const bf16x8*)(Vb + (hs + ht * 16 + l15) * K2_VSTR + kk * 64 + g * 16);
        o[0][ht] = __builtin_amdgcn_mfma_f32_16x16x32_bf16(pa0, vb, o[0][ht], 0, 0, 0);
        o[1][ht] = __builtin_amdgcn_mfma_f32_16x16x32_bf16(pa1, vb, o[1][ht], 0, 0, 0);
      }
    }
  }
  __syncthreads();

  #pragma unroll
  for (int i2 = 0; i2 < 2; ++i2) {
    float inv[4];
    #pragma unroll
    for (int r = 0; r < 4; ++r) inv[r] = 1.f / lrun[i2 * 16 + g * 4 + r];
    #pragma unroll
    for (int ht = 0; ht < 4; ++ht)
      #pragma unroll
      for (int r = 0; r < 4; ++r) {
        int row = i2 * 16 + g * 4 + r;
        int h = hs + ht * 16 + l15;
        Og[(size_t)row * NH + h] = o[i2][ht][r] * inv[r];
      }
  }
}

// ---------------------------------------------------------------------------
extern "C" void kernel_launch(void* const* d_in, const int* in_sizes, int n_in,
                              void* d_out, int out_size, void* d_ws, size_t ws_size,
                              hipStream_t stream) {
  const float* x  = (const float*)d_in[0];
  const float* Wq = (const float*)d_in[1];
  const float* Wk = (const float*)d_in[2];
  const float* Wv = (const float*)d_in[3];
  float* out = (float*)d_out;
  char* ws = (char*)d_ws;

  size_t off = 0;
  __bf16* wT   = (__bf16*)(ws + off); off += (size_t)3 * ND * NH * 2;   // 1.5 MB
  __bf16* p_ws = (__bf16*)(ws + off); off += (size_t)NROWS * NH * 2;    // 64 MB
  __bf16* k_ws = (__bf16*)(ws + off); off += (size_t)NROWS * NH * 2;    // 64 MB
  __bf16* vT_ws= (__bf16*)(ws + off); off += (size_t)NROWS * NH * 2;    // 64 MB
  float*  L_ws = (float*)(ws + off);  off += (size_t)NROWS * 4;         // 0.25 MB

  prep_w<<<dim3(512), dim3(256), 0, stream>>>(Wq, Wk, Wv, wT);
  proj_kernel<<<dim3(2048, 3), dim3(512), 0, stream>>>(x, wT, p_ws, k_ws, L_ws, vT_ws);
  attn_kernel<<<dim3(2048), dim3(512), 0, stream>>>(p_ws, k_ws, L_ws, vT_ws, out);
}

// Round 2
// 997.594 us; speedup vs baseline: 1.5658x; 1.5658x over previous
//
#include <hip/hip_runtime.h>
#include <hip/hip_bf16.h>

typedef __bf16 bf16x8 __attribute__((ext_vector_type(8)));
typedef float  f32x4  __attribute__((ext_vector_type(4)));

#define NB 32
#define NS 2048
#define ND 512
#define NH 512
#define NROWS (NB*NS)
#define L2E 1.44269504f

__device__ __forceinline__ void gload16(const void* g, void* l) {
  __builtin_amdgcn_global_load_lds((const __attribute__((address_space(1))) void*)g,
                                   (__attribute__((address_space(3))) void*)l, 16, 0, 0);
}

__device__ __forceinline__ bf16x8 mfma_bf16(bf16x8 a, bf16x8 b);  // unused decl guard

// ---------------------------------------------------------------------------
// prep: W[d][h] (f32) -> wT[m][h][d] (bf16)
// ---------------------------------------------------------------------------
__global__ void prep_w(const float* __restrict__ Wq, const float* __restrict__ Wk,
                       const float* __restrict__ Wv, __bf16* __restrict__ wT) {
  int i = blockIdx.x * blockDim.x + threadIdx.x;
  const int total = 3 * ND * NH;
  for (; i < total; i += gridDim.x * blockDim.x) {
    int m = i / (ND * NH);
    int rem = i - m * (ND * NH);
    int h = rem >> 9;
    int d = rem & 511;
    const float* W = (m == 0) ? Wq : ((m == 1) ? Wk : Wv);
    wT[i] = (__bf16)W[(size_t)d * NH + h];
  }
}

// ---------------------------------------------------------------------------
// K1: fused 3-mode projection. 64 rows/block, x staged once (XOR-swizzled),
// W double-buffered via global_load_lds (source-XOR). 8 waves: rt=w>>1, cs=w&1.
// outputs: p (softmax(q)), k (raw) + L = logsumexp(k), v in tiled layout
//          vT_t[b][s>>3][h][s&7].
// ---------------------------------------------------------------------------
#define K1_XOFF 0            // x: [64][1024B], XOR-swizzled segs
#define K1_WOFF 65536        // W: 2 x [512][64B] (source-XOR staged)
#define K1_REDM 131072       // [2][64] f32
#define K1_REDS 131584       // [2][64] f32
#define K1_LDS  132096

__global__ __launch_bounds__(512, 2)
void proj_kernel(const float* __restrict__ x, const __bf16* __restrict__ wT,
                 __bf16* __restrict__ p_out, __bf16* __restrict__ k_out,
                 float* __restrict__ L_out, __bf16* __restrict__ vt_out)
{
  __shared__ __align__(16) char smem[K1_LDS];
  char* xb = smem + K1_XOFF;
  char* wb = smem + K1_WOFF;
  float* redm = (float*)(smem + K1_REDM);
  float* reds = (float*)(smem + K1_REDS);

  const int tid = threadIdx.x;
  const int lane = tid & 63, l15 = lane & 15, g = lane >> 4;
  const int w = tid >> 6, rt = w >> 1, cs = w & 1;
  const int r0 = blockIdx.x * 64;
  const int b = r0 >> 11, s0 = r0 & (NS - 1);

  // ---- stage x: [64 rows][512 d] f32 -> bf16, seg XOR (row&7) ----
  {
    int row = tid >> 3, sc = tid & 7;
    const float* xr = x + (size_t)(r0 + row) * ND;
    #pragma unroll
    for (int u = 0; u < 8; ++u) {
      int s = u * 8 + sc;
      float4 v0 = *(const float4*)(xr + s * 8);
      float4 v1 = *(const float4*)(xr + s * 8 + 4);
      bf16x8 cv;
      cv[0]=(__bf16)v0.x; cv[1]=(__bf16)v0.y; cv[2]=(__bf16)v0.z; cv[3]=(__bf16)v0.w;
      cv[4]=(__bf16)v1.x; cv[5]=(__bf16)v1.y; cv[6]=(__bf16)v1.z; cv[7]=(__bf16)v1.w;
      *(bf16x8*)(xb + row * 1024 + ((s ^ (row & 7)) * 16)) = cv;
    }
  }
  // ---- issue W stage gs=0 ----
  {
    const __bf16* wsrc = wT;  // m=0, d0=0
    #pragma unroll
    for (int u = 0; u < 4; ++u) {
      int sid = u * 512 + tid, h = sid >> 2, gg = sid & 3;
      gload16(wsrc + (size_t)h * ND + ((gg ^ (h & 3)) * 8), wb + sid * 16);
    }
  }
  __syncthreads();

  for (int m = 0; m < 3; ++m) {
    f32x4 acc[16];
    #pragma unroll
    for (int ht = 0; ht < 16; ++ht) acc[ht] = (f32x4){0.f,0.f,0.f,0.f};

    for (int step = 0; step < 16; ++step) {
      int gs = m * 16 + step;
      char* wcur = wb + (gs & 1) * 32768;
      if (gs + 1 < 48) {                     // stage next W tile
        int gn = gs + 1, mn = gn >> 4, sn = gn & 15;
        const __bf16* wsrc = wT + (size_t)mn * (ND * NH) + sn * 32;
        char* wdst = wb + (gn & 1) * 32768;
        #pragma unroll
        for (int u = 0; u < 4; ++u) {
          int sid = u * 512 + tid, h = sid >> 2, gg = sid & 3;
          gload16(wsrc + (size_t)h * ND + ((gg ^ (h & 3)) * 8), wdst + sid * 16);
        }
      }
      int arow = rt * 16 + l15;
      bf16x8 a = *(const bf16x8*)(xb + arow * 1024 + (((step * 4 + g) ^ (arow & 7)) * 16));
      #pragma unroll
      for (int ht = 0; ht < 16; ++ht) {
        int h = cs * 256 + ht * 16 + l15;
        bf16x8 bb = *(const bf16x8*)(wcur + h * 64 + ((g ^ (h & 3)) * 16));
        acc[ht] = __builtin_amdgcn_mfma_f32_16x16x32_bf16(a, bb, acc[ht], 0, 0, 0);
      }
      __syncthreads();   // drains vmcnt: next W landed; all waves done with wcur
    }

    // ---- epilogue mode m; lane holds rows rt*16+g*4+r, cols cs*256+ht*16+l15
    if (m == 2) {
      // v: write tiled vT_t[b][sg][h][s&7], 8B per (ht) store
      int sgg = (s0 >> 3) + rt * 2 + (g >> 1);
      size_t basep = ((size_t)(b * 256 + sgg)) * 512;
      #pragma unroll
      for (int ht = 0; ht < 16; ++ht) {
        int h = cs * 256 + ht * 16 + l15;
        union { __bf16 h4[4]; ushort4 u4; } cv;
        #pragma unroll
        for (int r = 0; r < 4; ++r) cv.h4[r] = (__bf16)acc[ht][r];
        *(ushort4*)(vt_out + (basep + h) * 8 + (g & 1) * 4) = cv.u4;
      }
    } else {
      float rmax[4], mrow[4], tsum[4];
      #pragma unroll
      for (int r = 0; r < 4; ++r) {
        float v = acc[0][r];
        #pragma unroll
        for (int ht = 1; ht < 16; ++ht) v = fmaxf(v, acc[ht][r]);
        v = fmaxf(v, __shfl_xor(v, 1)); v = fmaxf(v, __shfl_xor(v, 2));
        v = fmaxf(v, __shfl_xor(v, 4)); v = fmaxf(v, __shfl_xor(v, 8));
        rmax[r] = v;
      }
      if (l15 == 0) {
        #pragma unroll
        for (int r = 0; r < 4; ++r) redm[cs * 64 + rt * 16 + g * 4 + r] = rmax[r];
      }
      __syncthreads();
      #pragma unroll
      for (int r = 0; r < 4; ++r) {
        int row = rt * 16 + g * 4 + r;
        mrow[r] = fmaxf(redm[row], redm[64 + row]);
      }
      #pragma unroll
      for (int r = 0; r < 4; ++r) {
        float s = 0.f;
        #pragma unroll
        for (int ht = 0; ht < 16; ++ht) s += exp2f((acc[ht][r] - mrow[r]) * L2E);
        s += __shfl_xor(s, 1); s += __shfl_xor(s, 2);
        s += __shfl_xor(s, 4); s += __shfl_xor(s, 8);
        tsum[r] = s;
        if (l15 == 0) reds[cs * 64 + rt * 16 + g * 4 + r] = s;
      }
      __syncthreads();
      #pragma unroll
      for (int r = 0; r < 4; ++r) {
        int row = rt * 16 + g * 4 + r;
        tsum[r] = reds[row] + reds[64 + row];
      }
      __bf16* dst = (m == 0) ? p_out : k_out;
      if (m == 0) {
        float inv[4];
        #pragma unroll
        for (int r = 0; r < 4; ++r) inv[r] = 1.f / tsum[r];
        #pragma unroll
        for (int ht = 0; ht < 16; ++ht) {
          int col = cs * 256 + ht * 16 + l15;
          #pragma unroll
          for (int r = 0; r < 4; ++r) {
            int row = rt * 16 + g * 4 + r;
            dst[(size_t)(r0 + row) * NH + col] =
                (__bf16)(exp2f((acc[ht][r] - mrow[r]) * L2E) * inv[r]);
          }
        }
      } else {
        #pragma unroll
        for (int ht = 0; ht < 16; ++ht) {
          int col = cs * 256 + ht * 16 + l15;
          #pragma unroll
          for (int r = 0; r < 4; ++r) {
            int row = rt * 16 + g * 4 + r;
            dst[(size_t)(r0 + row) * NH + col] = (__bf16)acc[ht][r];
          }
        }
        if (cs == 0 && l15 == 0) {
          #pragma unroll
          for (int r = 0; r < 4; ++r) {
            int row = rt * 16 + g * 4 + r;
            L_out[r0 + row] = mrow[r] + __logf(tsum[r]);
          }
        }
      }
      __syncthreads();   // reds/redm free for next mode
    }
  }
}

// ---------------------------------------------------------------------------
// K2: attention. scores[i][j] = dot(p_i,k_j) - L[j] <= 0 always, so NO online
// max: w = exp2(s*log2e - L*log2e), lsum accumulated per-lane, reduced once.
// BI=64, BJ=32, 64 steps, K+V double-buffered via global_load_lds with
// pre-swizzled sources; P routed through padded LDS. 2 barriers/step.
// 8 waves: it=w>>1 (i 16-tile), jt=w&1 (scores j-half / PV h-half 256).
// ---------------------------------------------------------------------------
#define K2_KOFF 0            // 2 x [32 j][1024B], seg XOR (j&7)
#define K2_VOFF 65536        // 2 x [512 h][64B], seg XOR (h&3)
#define K2_POFF 131072       // [64][72B]
#define K2_LOFF 135680       // [2][64] f32
#define K2_LDS  136192

__global__ __launch_bounds__(512, 2)
void attn_kernel(const __bf16* __restrict__ p_all, const __bf16* __restrict__ k_all,
                 const float* __restrict__ L_all, const __bf16* __restrict__ vt_all,
                 float* __restrict__ out)
{
  __shared__ __align__(16) char smem[K2_LDS];
  char* Pb = smem + K2_POFF;
  float* lred = (float*)(smem + K2_LOFF);

  const int bid = blockIdx.x;
  const int lb = (bid & 7) * 128 + (bid >> 3);       // XCD swizzle, 1024 = 8*128
  const int b = lb >> 5, ib = lb & 31;
  const int i0 = ib * 64;

  const __bf16* Pg = p_all + (size_t)b * NS * NH;
  const __bf16* Kg = k_all + (size_t)b * NS * NH;
  const float*  Lg = L_all + (size_t)b * NS;
  const __bf16* Vg = vt_all + (size_t)b * (256 * 512 * 8);
  float* Og = out + ((size_t)b * NS + i0) * NH;

  const int tid = threadIdx.x;
  const int lane = tid & 63, l15 = lane & 15, g = lane >> 4;
  const int w = tid >> 6, it = w >> 1, jt = w & 1;

  // Q fragments: rows i0 + it*16 + l15, 16 k-slices
  bf16x8 qf[16];
  {
    const __bf16* qrow = Pg + (size_t)(i0 + it * 16 + l15) * NH + g * 8;
    #pragma unroll
    for (int kk = 0; kk < 16; ++kk) qf[kk] = *(const bf16x8*)(qrow + kk * 32);
  }

  f32x4 o[16];
  #pragma unroll
  for (int ht = 0; ht < 16; ++ht) o[ht] = (f32x4){0.f,0.f,0.f,0.f};
  float lsum[4] = {0.f, 0.f, 0.f, 0.f};

  // ---- prologue: stage t=0 into buf0 ----
  #pragma unroll
  for (int u = 0; u < 4; ++u) {
    int sid = u * 512 + tid, j = sid >> 6, s6 = sid & 63;
    gload16(Kg + (size_t)j * NH + ((s6 ^ (j & 7)) * 8), smem + K2_KOFF + sid * 16);
  }
  #pragma unroll
  for (int u = 0; u < 4; ++u) {
    int sid = u * 512 + tid, h = sid >> 2, jg = sid & 3;
    gload16(Vg + ((size_t)(jg ^ (h & 3)) * 512 + h) * 8, smem + K2_VOFF + sid * 16);
  }
  __syncthreads();

  for (int t = 0; t < NS / 32; ++t) {
    const int cur = t & 1;
    char* Kb = smem + K2_KOFF + cur * 32768;
    char* Vb = smem + K2_VOFF + cur * 32768;

    if (t + 1 < NS / 32) {                    // stage t+1 into other buffer
      const __bf16* Ks = Kg + (size_t)(t + 1) * 32 * NH;
      char* Kd = smem + K2_KOFF + (cur ^ 1) * 32768;
      #pragma unroll
      for (int u = 0; u < 4; ++u) {
        int sid = u * 512 + tid, j = sid >> 6, s6 = sid & 63;
        gload16(Ks + (size_t)j * NH + ((s6 ^ (j & 7)) * 8), Kd + sid * 16);
      }
      char* Vd = smem + K2_VOFF + (cur ^ 1) * 32768;
      #pragma unroll
      for (int u = 0; u < 4; ++u) {
        int sid = u * 512 + tid, h = sid >> 2, jg = sid & 3;
        int sg = (t + 1) * 4 + (jg ^ (h & 3));
        gload16(Vg + ((size_t)sg * 512 + h) * 8, Vd + sid * 16);
      }
    }
    float LB = Lg[t * 32 + jt * 16 + l15] * L2E;

    // ---- scores: 16x16 tile per wave ----
    f32x4 s = (f32x4){0.f,0.f,0.f,0.f};
    {
      const int jrow = jt * 16 + l15;
      const char* kbase = Kb + jrow * 1024;
      const int jx = jrow & 7;
      #pragma unroll
      for (int kk = 0; kk < 16; ++kk) {
        bf16x8 kf = *(const bf16x8*)(kbase + (((kk * 4 + g) ^ jx) * 16));
        s = __builtin_amdgcn_mfma_f32_16x16x32_bf16(qf[kk], kf, s, 0, 0, 0);
      }
    }
    // ---- weights + P write (packed pairs) ----
    float pv[4];
    #pragma unroll
    for (int r = 0; r < 4; ++r) {
      pv[r] = exp2f(s[r] * L2E - LB);
      lsum[r] += pv[r];
    }
    #pragma unroll
    for (int r = 0; r < 4; ++r) {
      float other = __shfl_xor(pv[r], 1);
      if ((l15 & 1) == 0) {
        union { __bf16 h; unsigned short u; } lo, hi;
        lo.h = (__bf16)pv[r]; hi.h = (__bf16)other;
        unsigned int pk = (unsigned int)lo.u | ((unsigned int)hi.u << 16);
        *(unsigned int*)(Pb + (it * 16 + g * 4 + r) * 72 + (jt * 16 + l15) * 2) = pk;
      }
    }
    __syncthreads();   // B1: P visible; next-tile K/V landed (vmcnt drain)

    // ---- PV: o[16 rows][256 cols per wave] ----
    {
      bf16x8 pa = *(const bf16x8*)(Pb + (it * 16 + l15) * 72 + g * 16);
      #pragma unroll
      for (int ht = 0; ht < 16; ++ht) {
        int h = jt * 256 + ht * 16 + l15;
        bf16x8 vb = *(const bf16x8*)(Vb + h * 64 + ((g ^ (h & 3)) * 16));
        o[ht] = __builtin_amdgcn_mfma_f32_16x16x32_bf16(pa, vb, o[ht], 0, 0, 0);
      }
    }
    __syncthreads();   // B2: done reading cur buffers / P
  }

  // ---- final row-sum reduce + normalize + write ----
  #pragma unroll
  for (int r = 0; r < 4; ++r) {
    float v = lsum[r];
    v += __shfl_xor(v, 1); v += __shfl_xor(v, 2);
    v += __shfl_xor(v, 4); v += __shfl_xor(v, 8);
    lsum[r] = v;
  }
  if (l15 == 0) {
    #pragma unroll
    for (int r = 0; r < 4; ++r) lred[jt * 64 + it * 16 + g * 4 + r] = lsum[r];
  }
  __syncthreads();
  float inv[4];
  #pragma unroll
  for (int r = 0; r < 4; ++r) {
    int rl = it * 16 + g * 4 + r;
    inv[r] = 1.f / (lred[rl] + lred[64 + rl]);
  }
  #pragma unroll
  for (int ht = 0; ht < 16; ++ht) {
    #pragma unroll
    for (int r = 0; r < 4; ++r) {
      Og[(size_t)(it * 16 + g * 4 + r) * NH + jt * 256 + ht * 16 + l15] = o[ht][r] * inv[r];
    }
  }
}

// ---------------------------------------------------------------------------
extern "C" void kernel_launch(void* const* d_in, const int* in_sizes, int n_in,
                              void* d_out, int out_size, void* d_ws, size_t ws_size,
                              hipStream_t stream) {
  const float* x  = (const float*)d_in[0];
  const float* Wq = (const float*)d_in[1];
  const float* Wk = (const float*)d_in[2];
  const float* Wv = (const float*)d_in[3];
  float* out = (float*)d_out;
  char* ws = (char*)d_ws;

  size_t off = 0;
  __bf16* wT   = (__bf16*)(ws + off); off += (size_t)3 * ND * NH * 2;   // 1.5 MB
  __bf16* p_ws = (__bf16*)(ws + off); off += (size_t)NROWS * NH * 2;    // 64 MB
  __bf16* k_ws = (__bf16*)(ws + off); off += (size_t)NROWS * NH * 2;    // 64 MB
  __bf16* vt_ws= (__bf16*)(ws + off); off += (size_t)NROWS * NH * 2;    // 64 MB (tiled)
  float*  L_ws = (float*)(ws + off);  off += (size_t)NROWS * 4;         // 0.25 MB

  prep_w<<<dim3(512), dim3(256), 0, stream>>>(Wq, Wk, Wv, wT);
  proj_kernel<<<dim3(1024), dim3(512), 0, stream>>>(x, wT, p_ws, k_ws, L_ws, vt_ws);
  attn_kernel<<<dim3(1024), dim3(512), 0, stream>>>(p_ws, k_ws, L_ws, vt_ws, out);
}